// Round 5
// baseline (36038.721 us; speedup 1.0000x reference)
//
#include <hip/hip_runtime.h>

// ---------------------------------------------------------------------------
// Graves handwriting synthesis: 3x peephole-LSTM(400) + soft window attention
// + MDN head.  B=32, T=400.  Persistent kernel.
//
// Round 5 changes vs round 4:
//  * ONE grid barrier per step (403 total vs 802): every block computes the
//    attention window redundantly (deterministic: identical inputs+code =>
//    identical w on all blocks), so phase k computes w(k-1), h1(k), h2(k-1),
//    h3(k-2) in a software pipeline with a single barrier.
//  * Decentralized all-see-all barrier with ZERO atomics: block i stores its
//    epoch to its own 64B line; 64 threads/block poll all 200 lines in
//    parallel. No RMW serialization, no release fan-out chain.
//  * h1(k-1) staged into LDS once per phase (coalesced float4), feeding both
//    the attention matmul and the z1/z2 h1-dots.
//  * Rationale: rounds 1-4 showed phase cost ~40us invariant under barrier
//    restructure, with bimodal 34/65ms timings => DVFS at 9.6% VALUBusy.
//    Fewer barriers + denser compute + atomic-free sync attacks all of it.
// ---------------------------------------------------------------------------

#define NBLK   200
#define NTHR   512
#define TSTEPS 400
#define BATCH  32
#define UNITSN 400
#define NCHARS 73
#define UC     50
#define KTOT   2228   // 476 (z1) + 876 (z2) + 876 (z3)

typedef unsigned int       u32;
typedef unsigned long long u64;

// ---- ws byte layout ----
// [0, 16384): per-block barrier flag lines (block i at int i*16); memset 0.
#define FLAG_BYTES 16384
#define WT_BYTE   16384                           // WT[1600][KTOT] fp32
#define H1_BYTE   (WT_BYTE + 1600 * KTOT * 4)     // + 14,259,200
#define HSLOT     12832                           // fp32 elems/slot (12800+32 pad)
#define H2_BYTE   (H1_BYTE + 400 * HSLOT * 4)
#define H3_BYTE   (H2_BYTE + 400 * HSLOT * 4)
// end of ws usage: H3_BYTE + 400*HSLOT*4 ~= 75.9 MB

__device__ __forceinline__ float sigf(float x)   { return 1.0f / (1.0f + __expf(-x)); }
__device__ __forceinline__ float tanhf_(float x) { return 1.0f - 2.0f / (1.0f + __expf(2.0f * x)); }

// 200-element dot (kh half of 400), both pointers any addrspace (inlined)
__device__ __forceinline__ float dot400(const float* __restrict__ w,
                                        const float* __restrict__ x, int kh) {
  const float4* wv = (const float4*)(w + kh * 200);
  const float4* xv = (const float4*)(x + kh * 200);
  float s0 = 0.f, s1 = 0.f, s2 = 0.f, s3 = 0.f;
#pragma unroll 5
  for (int i = 0; i < 50; ++i) {
    float4 a = wv[i], bb = xv[i];
    s0 = fmaf(a.x, bb.x, s0); s1 = fmaf(a.y, bb.y, s1);
    s2 = fmaf(a.z, bb.z, s2); s3 = fmaf(a.w, bb.w, s3);
  }
  return (s0 + s1) + (s2 + s3);
}

__device__ __forceinline__ float dot73(const float* __restrict__ w,
                                       const float* __restrict__ x, int kh) {
  int st = kh * 37, en = st + (kh ? 36 : 37);
  float s = 0.f;
  for (int k = st; k < en; ++k) s = fmaf(w[k], x[k], s);
  return s;
}

extern "C" __global__ void __launch_bounds__(NTHR, 1)
hand_kernel(const float* __restrict__ xs, const int* __restrict__ chars,
            const int* __restrict__ lens,
            const float* __restrict__ Wx0, const float* __restrict__ Wh0,
            const float* __restrict__ b0, const float* __restrict__ p0,
            const float* __restrict__ Wx1, const float* __restrict__ Wh1,
            const float* __restrict__ b1, const float* __restrict__ p1,
            const float* __restrict__ Wx2, const float* __restrict__ Wh2,
            const float* __restrict__ b2, const float* __restrict__ p2,
            const float* __restrict__ Watt, const float* __restrict__ batt,
            const float* __restrict__ Wmdn, const float* __restrict__ bmdn,
            float* __restrict__ dout, char* __restrict__ wsb) {
  const int blk = blockIdx.x;
  const int tid = threadIdx.x;

  __shared__ float h1L[BATCH * 404];        // staged h1(k-1), row pad 404
  __shared__ float wbufs[2][BATCH * NCHARS];// w(k-1)/w(k-2) ping-pong
  __shared__ float zpart[NTHR];
  __shared__ float zbuf[256];
  __shared__ float attL[BATCH * 30];
  __shared__ float alphaL[320], betaL[320], kappaL[320];
  __shared__ float biasL[3][8];
  __shared__ float peepL[3][3][2];
  __shared__ float cstate[3][64];           // [layer][ul*32 + b]
  __shared__ short charL[BATCH * UC];
  __shared__ int   lensL[BATCH];
  __shared__ float tbuf[64][65];            // one-time transpose tile

  int*   flags = (int*)wsb;
  float* wt    = (float*)(wsb + WT_BYTE);
  float* h1h   = (float*)(wsb + H1_BYTE);
  float* h2h   = (float*)(wsb + H2_BYTE);
  float* h3h   = (float*)(wsb + H3_BYTE);

  const int out = tid & 255;
  const int b   = out >> 3;    // batch 0..31
  const int c   = out & 7;     // col: (c>>2)=unit_local, (c&3)=gate (i,f,g,o)
  const int kh  = tid >> 8;    // k-half 0/1 (uniform per wave)
  const int u0  = 2 * blk;

  if (tid < 192) cstate[tid / 64][tid % 64] = 0.f;
  if (tid < 320) kappaL[tid] = 0.f;
  for (int i = tid; i < BATCH * UC; i += NTHR) charL[i] = (short)chars[i];
  if (tid < BATCH) lensL[tid] = lens[tid];

  // ---- one-time: tiled transpose of stacked [Wx;Wh] into WT[col][KTOT] ----
  // relaxed agent-scope write-through stores; WT immutable afterwards.
  {
    const int nct = 1600 / 64;                 // 25 col tiles
    const int nkt = (KTOT + 63) / 64;          // 35 k tiles
    const int lc  = tid & 63;
    const int lr0 = tid >> 6;                  // 0..7
    for (int tile = blk; tile < nkt * nct; tile += NBLK) {
      int kt = tile / nct, ct = tile - kt * nct;
      int k0 = kt * 64, c0 = ct * 64;
      for (int rr = lr0; rr < 64; rr += 8) {
        int k = k0 + rr;
        float v = 0.f;
        if (k < KTOT) {
          const float* rp;
          if (k < 476)        rp = (k < 76) ? Wx0 + (size_t)k * 1600 : Wh0 + (size_t)(k - 76) * 1600;
          else if (k < 1352) { int kk = k - 476;  rp = (kk < 476) ? Wx1 + (size_t)kk * 1600 : Wh1 + (size_t)(kk - 476) * 1600; }
          else               { int kk = k - 1352; rp = (kk < 476) ? Wx2 + (size_t)kk * 1600 : Wh2 + (size_t)(kk - 476) * 1600; }
          v = rp[c0 + lc];
        }
        tbuf[rr][lc] = v;
      }
      __syncthreads();
      for (int cc = lr0; cc < 64; cc += 8) {
        int k = k0 + lc;
        if (k < KTOT)
          __hip_atomic_store(&wt[(size_t)(c0 + cc) * KTOT + k], tbuf[lc][cc],
                             __ATOMIC_RELAXED, __HIP_MEMORY_SCOPE_AGENT);
      }
      __syncthreads();
    }
  }

  if (tid < 24) {
    int l = tid >> 3, cc = tid & 7;
    const float* bs = (l == 0) ? b0 : (l == 1) ? b1 : b2;
    biasL[l][cc] = bs[(cc & 3) * UNITSN + u0 + (cc >> 2)];
  }
  if (tid < 18) {
    int l = tid / 6, r = (tid % 6) >> 1, ul = tid & 1;
    const float* ps = (l == 0) ? p0 : (l == 1) ? p1 : p2;
    peepL[l][r][ul] = ps[r * UNITSN + u0 + ul];
  }
  __syncthreads();

  // ---- decentralized all-see-all grid barrier: no atomic RMW at all ----
  // block i: store epoch to own line; 64 threads poll all 200 lines.
  int epoch = 0;
  auto gridbar = [&](int e) {
    __syncthreads();   // drains each wave's vmcnt -> stores globally visible
    if (tid == 0)
      __hip_atomic_store(&flags[blk * 16], e, __ATOMIC_RELAXED, __HIP_MEMORY_SCOPE_AGENT);
    if (tid < 64) {
      for (int f = tid; f < NBLK; f += 64)
        while (__hip_atomic_load(&flags[f * 16], __ATOMIC_RELAXED, __HIP_MEMORY_SCOPE_AGENT) < e)
          __builtin_amdgcn_s_sleep(2);
    }
    __syncthreads();
  };

  // finalize: LDS-reduce z, gate math, write h (2 units, one 8B store) to slot
  auto finalize = [&](int layer, float acc, float* hdst) {
    zpart[tid] = acc;
    __syncthreads();
    if (tid < 256) zbuf[tid] = zpart[tid] + zpart[tid + 256] + biasL[layer][tid & 7];
    __syncthreads();
    if (tid < 256 && (tid & 7) == 0) {
      int bb = tid >> 3;
      union { float f[2]; u64 v; } pk;
#pragma unroll
      for (int ul = 0; ul < 2; ++ul) {
        float zi = zbuf[tid + ul * 4 + 0], zf = zbuf[tid + ul * 4 + 1];
        float zg = zbuf[tid + ul * 4 + 2], zo = zbuf[tid + ul * 4 + 3];
        float cold = cstate[layer][ul * 32 + bb];
        float ig = sigf(zi + peepL[layer][0][ul] * cold);
        float fg = sigf(zf + peepL[layer][1][ul] * cold);
        float cn = fg * cold + ig * tanhf_(zg);
        float og = sigf(zo + peepL[layer][2][ul] * cn);
        float h  = og * tanhf_(cn);
        cstate[layer][ul * 32 + bb] = cn;
        pk.f[ul] = h;
      }
      __hip_atomic_store((u64*)(hdst + bb * UNITSN + u0), pk.v,
                         __ATOMIC_RELAXED, __HIP_MEMORY_SCOPE_AGENT);
    }
    __syncthreads();
  };

  // attention: w from h1L (staged).  Deterministic per block; no atomic matmul.
  auto attention = [&](float* wc) {
    if (tid < 480) {                       // 30 j x 16 bb, 2 batches each
      int j = tid >> 4, bb = tid & 15;
      const float* h0 = h1L + bb * 404;
      const float* h1p = h1L + (bb + 16) * 404;
      float a0 = 0.f, a1 = 0.f;
      for (int k2 = 0; k2 < 400; ++k2) {
        float wv = Watt[k2 * 30 + j];
        a0 = fmaf(h0[k2], wv, a0);
        a1 = fmaf(h1p[k2], wv, a1);
      }
      attL[bb * 30 + j] = a0;
      attL[(bb + 16) * 30 + j] = a1;
    }
    for (int i = tid; i < BATCH * NCHARS; i += NTHR) wc[i] = 0.f;
    __syncthreads();
    if (tid < 320) {
      int bb = tid / 10, j = tid - bb * 10;
      alphaL[tid] = __expf(attL[bb * 30 + j]      + batt[j]);
      betaL[tid]  = __expf(attL[bb * 30 + 10 + j] + batt[10 + j]);
      kappaL[tid] = kappaL[tid] + __expf(attL[bb * 30 + 20 + j] + batt[20 + j]);
    }
    __syncthreads();
    for (int idx = tid; idx < BATCH * UC; idx += NTHR) {
      int bb = idx / UC, u = idx - bb * UC;
      if (u < lensL[bb]) {
        float ph = 0.f;
#pragma unroll
        for (int j = 0; j < 10; ++j) {
          float d = kappaL[bb * 10 + j] - (float)u;
          ph = fmaf(alphaL[bb * 10 + j], __expf(-betaL[bb * 10 + j] * d * d), ph);
        }
        atomicAdd(&wc[bb * NCHARS + charL[bb * UC + u]], ph);
      }
    }
    __syncthreads();
  };

  const float* Wc0 = wt + (size_t)((c & 3) * UNITSN + u0 + (c >> 2)) * KTOT;

  gridbar(++epoch);  // WT ready

  // ---- phase 0: h1(0) from x(0) only (h,c,w all zero) ----
  {
    float acc = 0.f;
    if (kh == 0) {
      const float* xr = xs + (b * TSTEPS + 0) * 3;
      acc = Wc0[0] * xr[0] + Wc0[1] * xr[1] + Wc0[2] * xr[2];
    }
    finalize(0, acc, h1h);
  }
  gridbar(++epoch);

  // ---- pipeline: phase k computes w(k-1), h1(k), h2(k-1), h3(k-2) ----
  for (int k = 1; k <= TSTEPS + 1; ++k) {
    float* wc = wbufs[k & 1];          // w(k-1), written this phase
    float* wp = wbufs[(k & 1) ^ 1];    // w(k-2), written last phase
    if (k <= TSTEPS) {
      // stage h1(k-1) into LDS (coalesced float4; rows padded to 404)
      const float4* src = (const float4*)(h1h + (size_t)(k - 1) * HSLOT);
      for (int i = tid; i < 3200; i += NTHR) {
        int bb = i / 100, off = i - bb * 100;
        ((float4*)(h1L + bb * 404))[off] = src[i];
      }
      __syncthreads();
      attention(wc);                   // w(k-1)
    }
    // z1 -> h1(k)
    if (k <= TSTEPS - 1) {
      float a1 = dot400(Wc0 + 76, h1L + b * 404, kh)
               + dot73(Wc0 + 3, wc + b * NCHARS, kh);
      if (kh == 0) {
        const float* xr = xs + (b * TSTEPS + k) * 3;
        a1 += Wc0[0] * xr[0] + Wc0[1] * xr[1] + Wc0[2] * xr[2];
      }
      finalize(0, a1, h1h + (size_t)k * HSLOT);
    }
    // z2 -> h2(k-1)
    if (k <= TSTEPS) {
      float a2 = dot400(Wc0 + 552, h1L + b * 404, kh)
               + dot73(Wc0 + 479, wc + b * NCHARS, kh);
      if (k >= 2) a2 += dot400(Wc0 + 952, h2h + (size_t)(k - 2) * HSLOT + b * UNITSN, kh);
      if (kh == 0) {
        const float* xr = xs + (b * TSTEPS + (k - 1)) * 3;
        a2 += Wc0[476] * xr[0] + Wc0[477] * xr[1] + Wc0[478] * xr[2];
      }
      finalize(1, a2, h2h + (size_t)(k - 1) * HSLOT);
    }
    // z3 -> h3(k-2)
    if (k >= 2) {
      float a3 = dot400(Wc0 + 1428, h2h + (size_t)(k - 2) * HSLOT + b * UNITSN, kh)
               + dot73(Wc0 + 1355, wp + b * NCHARS, kh);
      if (k >= 3) a3 += dot400(Wc0 + 1828, h3h + (size_t)(k - 3) * HSLOT + b * UNITSN, kh);
      if (kh == 0) {
        const float* xr = xs + (b * TSTEPS + (k - 2)) * 3;
        a3 += Wc0[1352] * xr[0] + Wc0[1353] * xr[1] + Wc0[1354] * xr[2];
      }
      finalize(2, a3, h3h + (size_t)(k - 2) * HSLOT);
    }
    gridbar(++epoch);
  }

  // ---- MDN head + output transforms (parallel over 12800 (b,t) rows) ----
  {
    int j = tid & 127, ks = tid >> 7;
    for (int i0 = 0; i0 < 64; i0 += 4) {
      float acc[4] = {0.f, 0.f, 0.f, 0.f};
      const float* hp[4];
      for (int r = 0; r < 4; ++r) {
        int row = blk + (i0 + r) * NBLK;
        hp[r] = h3h + (size_t)(row % TSTEPS) * HSLOT + (row / TSTEPS) * UNITSN + ks * 100;
      }
      if (j < 121) {
        const float* wp2 = Wmdn + (ks * 100) * 121 + j;
        for (int k = 0; k < 100; ++k) {
          float wv = wp2[(size_t)k * 121];
#pragma unroll
          for (int r = 0; r < 4; ++r) acc[r] = fmaf(hp[r][k], wv, acc[r]);
        }
      }
      for (int r = 0; r < 4; ++r) {
        zpart[tid] = acc[r];
        __syncthreads();
        if (tid < 121)
          zbuf[tid] = zpart[tid] + zpart[tid + 128] + zpart[tid + 256] + zpart[tid + 384] + bmdn[tid];
        __syncthreads();
        if (tid == 0) {
          float mx = zbuf[0];
          for (int q = 1; q < 20; ++q) mx = fmaxf(mx, zbuf[q]);
          float s = 0.f;
          for (int q = 0; q < 20; ++q) s += __expf(zbuf[q] - mx);
          zbuf[126] = mx;
          zbuf[127] = 1.f / s;
        }
        __syncthreads();
        if (tid < 121) {
          int row = blk + (i0 + r) * NBLK;
          float y = zbuf[tid], o;
          if (tid < 20)       o = __expf(y - zbuf[126]) * zbuf[127];  // softmax(pi)
          else if (tid < 60)  o = y;                                   // mu1, mu2
          else if (tid < 100) o = __expf(y);                           // s1, s2
          else if (tid < 120) o = tanhf_(y);                           // rho
          else                o = sigf(y);                             // eos
          dout[(size_t)row * 121 + tid] = o;
        }
        __syncthreads();
      }
    }
  }
}

extern "C" void kernel_launch(void* const* d_in, const int* in_sizes, int n_in,
                              void* d_out, int out_size, void* d_ws, size_t ws_size,
                              hipStream_t stream) {
  const float* xs   = (const float*)d_in[0];
  const int*   chrs = (const int*)d_in[1];
  const int*   lens = (const int*)d_in[2];
  const float* Wx0  = (const float*)d_in[3];
  const float* Wh0  = (const float*)d_in[4];
  const float* b0   = (const float*)d_in[5];
  const float* p0   = (const float*)d_in[6];
  const float* Wx1  = (const float*)d_in[7];
  const float* Wh1  = (const float*)d_in[8];
  const float* b1   = (const float*)d_in[9];
  const float* p1   = (const float*)d_in[10];
  const float* Wx2  = (const float*)d_in[11];
  const float* Wh2  = (const float*)d_in[12];
  const float* b2   = (const float*)d_in[13];
  const float* p2   = (const float*)d_in[14];
  const float* Watt = (const float*)d_in[15];
  const float* batt = (const float*)d_in[16];
  const float* Wmdn = (const float*)d_in[17];
  const float* bmdn = (const float*)d_in[18];

  // zero barrier flag lines only; everything else is write-once
  hipMemsetAsync(d_ws, 0, FLAG_BYTES, stream);
  hipLaunchKernelGGL(hand_kernel, dim3(NBLK), dim3(NTHR), 0, stream,
                     xs, chrs, lens, Wx0, Wh0, b0, p0, Wx1, Wh1, b1, p1,
                     Wx2, Wh2, b2, p2, Watt, batt, Wmdn, bmdn,
                     (float*)d_out, (char*)d_ws);
}